// Round 12
// baseline (57.379 us; speedup 1.0000x reference)
//
#include <hip/hip_runtime.h>
#include <cfloat>

#define BS 64
#define C  1024
#define D  64
#define CT 128

typedef __attribute__((ext_vector_type(8))) short short8;
typedef __attribute__((ext_vector_type(4))) float f32x4;
typedef unsigned short ushort_t;
typedef unsigned int uint_t;

__device__ __forceinline__ ushort_t f2bf(float f) {
    uint_t u = __float_as_uint(f);
    u += 0x7fffu + ((u >> 16) & 1u);          // round-to-nearest-even
    return (ushort_t)(u >> 16);
}

// ---- prep: bf16 prototypes frag-ordered (prot only, 8 blocks) ----
// short8 idx = jt*128 + h*64 + ln;  jt=k>>4, h=K-half, ln=(k&15)+kslot*16
__global__ void prep_prot(const float* __restrict__ prot, ushort_t* __restrict__ ph)
{
    const int k = blockIdx.x * 128 + threadIdx.x;   // 0..1023
    const float4* row = (const float4*)(prot + (size_t)k * D);
    const int jt = k >> 4;
    #pragma unroll
    for (int dg = 0; dg < 8; dg++) {
        float4 a = row[dg * 2];
        float4 b = row[dg * 2 + 1];
        float x[8] = {a.x, a.y, a.z, a.w, b.x, b.y, b.z, b.w};
        short8 hv;
        #pragma unroll
        for (int e = 0; e < 8; e++) hv[e] = (short)f2bf(x[e]);
        const int h  = dg >> 2;
        const int ln = (k & 15) + (dg & 3) * 16;
        ((short8*)ph)[(size_t)jt * 128 + h * 64 + ln] = hv;
    }
}

// ---- kernelA: partial argmax keys over one k-half (1024 blocks) ----
__global__ __launch_bounds__(512, 4)
void triplet_keys(const float* __restrict__ inputs,
                  const ushort_t* __restrict__ phg,
                  uint_t* __restrict__ pkeys)
{
    __shared__ short8 bsh[32 * 128];     // 64 KB; first 16 KB doubles as X stage
    __shared__ uint_t redk[CT][4];

    const int tid  = threadIdx.x;
    const int lane = tid & 63;
    const int wid  = tid >> 6;     // 0..7
    const int wr   = wid >> 2;     // 0..1 -> 64 c-rows
    const int wc   = wid & 3;      // 0..3 -> 8 col-tiles in this half
    const int blk  = blockIdx.x;
    const int kh   = blk & 1;                 // k-half
    const int ct   = (blk >> 1) & 7;          // c-tile
    const int b    = blk >> 4;                // batch
    const int c0   = ct * CT;

    const short8* BH = (const short8*)phg;

    // ---- prologue: convert this block's X (128 rows) to frag-order in LDS ----
    #pragma unroll
    for (int it = 0; it < 2; it++) {
        const int rel = tid + it * 512;       // 0..1023
        const int ft = rel >> 7, w = rel & 127, h = w >> 6, ln = w & 63;
        const int rr = ft * 16 + (ln & 15), dg = h * 4 + (ln >> 4);
        const float* s = inputs + (size_t)(b * C + c0 + rr) * D + dg * 8;
        float4 a  = *(const float4*)s;
        float4 b2 = *(const float4*)(s + 4);
        short8 hv;
        hv[0] = (short)f2bf(a.x);  hv[1] = (short)f2bf(a.y);
        hv[2] = (short)f2bf(a.z);  hv[3] = (short)f2bf(a.w);
        hv[4] = (short)f2bf(b2.x); hv[5] = (short)f2bf(b2.y);
        hv[6] = (short)f2bf(b2.z); hv[7] = (short)f2bf(b2.w);
        bsh[rel] = hv;
    }
    __syncthreads();

    // A fragments for this wave's 64 rows (lane-contiguous LDS reads)
    short8 ah[4][2];
    #pragma unroll
    for (int i = 0; i < 4; i++) {
        ah[i][0] = bsh[(wr * 4 + i) * 128 + lane];
        ah[i][1] = bsh[(wr * 4 + i) * 128 + 64 + lane];
    }
    __syncthreads();   // frag reads done before B stage overwrites

    // ---- stage this k-half of B (64 KB) ----
    const short8* src = BH + (size_t)kh * 4096;
    #pragma unroll
    for (int it = 0; it < 8; it++)
        bsh[it * 512 + tid] = src[it * 512 + tid];
    __syncthreads();

    uint_t bestk[16];
    #pragma unroll
    for (int q = 0; q < 16; q++) bestk[q] = 0u;

    const uint_t MMASK = 0xFFFFFC00u;
    const int rowtile0 = (c0 >> 4) + wr * 4;
    const int rsub = (lane >> 4) * 4;
    const int csub = lane & 15;

    auto process = [&](int jg, short8 b0, short8 b1) {
        const uint_t cidx = (uint_t)(1023 - (jg * 16 + csub));
        #pragma unroll
        for (int i = 0; i < 4; i++) {
            f32x4 acc = {16.f, 16.f, 16.f, 16.f};   // S_raw+16 > 0: sortable bits
            acc = __builtin_amdgcn_mfma_f32_16x16x32_bf16(ah[i][0], b0, acc, 0, 0, 0);
            acc = __builtin_amdgcn_mfma_f32_16x16x32_bf16(ah[i][1], b1, acc, 0, 0, 0);
            const bool dtile = (rowtile0 + i) == jg;   // wave-uniform
            #pragma unroll
            for (int r = 0; r < 4; r++) {
                uint_t key = (__float_as_uint(acc[r]) & MMASK) | cidx;
                if (dtile && (rsub + r) == csub) key = 0u;   // mask diagonal
                bestk[i * 4 + r] = bestk[i * 4 + r] > key ? bestk[i * 4 + r] : key;
            }
        }
    };

    // 8 tiles per wave from LDS, 1-deep register prefetch
    const int base = wc * 8;
    short8 cb0 = bsh[(base + 0) * 128 + lane];
    short8 cb1 = bsh[(base + 0) * 128 + 64 + lane];
    #pragma unroll
    for (int lt = 0; lt < 8; lt++) {
        const int nt = (lt + 1 < 8) ? lt + 1 : 7;
        short8 n0 = bsh[(base + nt) * 128 + lane];
        short8 n1 = bsh[(base + nt) * 128 + 64 + lane];
        __builtin_amdgcn_sched_barrier(0);
        process(kh * 32 + base + lt, cb0, cb1);
        cb0 = n0; cb1 = n1;
    }

    // cross-lane max over the 16 col-lanes
    #pragma unroll
    for (int i = 0; i < 4; i++)
        #pragma unroll
        for (int r = 0; r < 4; r++) {
            uint_t v = bestk[i * 4 + r];
            #pragma unroll
            for (int off = 1; off < 16; off <<= 1) {
                uint_t ov = (uint_t)__shfl_xor((int)v, off);
                v = v > ov ? v : ov;
            }
            if (csub == 0) redk[wr * 64 + i * 16 + rsub + r][wc] = v;
        }
    __syncthreads();

    // per-row partial key store (coalesced, no atomics)
    if (tid < CT) {
        uint_t k0 = redk[tid][0], k1 = redk[tid][1];
        uint_t k2 = redk[tid][2], k3 = redk[tid][3];
        uint_t kk = k0 > k1 ? k0 : k1;
        uint_t kl = k2 > k3 ? k2 : k3;
        kk = kk > kl ? kk : kl;
        pkeys[(size_t)kh * (BS * C) + b * C + c0 + tid] = kk;
    }
}

// ---- kernelB: exact fp32 epilogue per row (512 blocks x 512 thr, 4 thr/row) ----
__global__ __launch_bounds__(512)
void triplet_loss(const float* __restrict__ inputs,
                  const float* __restrict__ label,
                  const float* __restrict__ prot,
                  const uint_t* __restrict__ pkeys,
                  float* __restrict__ part)
{
    __shared__ float wred[16];

    const int tid  = threadIdx.x;
    const int lane = tid & 63;
    const int wid  = tid >> 6;
    const int blk  = blockIdx.x;
    const int b    = blk >> 3;
    const int c0   = (blk & 7) * CT;

    float num = 0.f, den = 0.f;
    {
        const int row = tid >> 2, p4 = tid & 3;
        const int gr = b * C + c0 + row;
        uint_t k0 = pkeys[gr];
        uint_t k1 = pkeys[(size_t)(BS * C) + gr];
        uint_t kk = k0 > k1 ? k0 : k1;
        const int bi = 1023 - (int)(kk & 0x3FFu);
        const int cg = c0 + row;

        const float4* xr = (const float4*)(inputs + (size_t)gr * D) + p4 * 4;
        float4 xv[4];
        float x2 = 0.f;
        #pragma unroll
        for (int q = 0; q < 4; q++) {
            xv[q] = xr[q];
            x2 = fmaf(xv[q].x, xv[q].x, fmaf(xv[q].y, xv[q].y,
                 fmaf(xv[q].z, xv[q].z, fmaf(xv[q].w, xv[q].w, x2))));
        }
        x2 += __shfl_xor(x2, 1);
        x2 += __shfl_xor(x2, 2);
        const float inv = 1.0f / fmaxf(sqrtf(x2), 1e-12f);

        const float4* pp = (const float4*)(prot + (size_t)cg * D) + p4 * 4;
        const float4* pn = (const float4*)(prot + (size_t)bi * D) + p4 * 4;
        float sap = 0.f, san = 0.f;
        #pragma unroll
        for (int q = 0; q < 4; q++) {
            float4 aa = pp[q];
            float4 nn = pn[q];
            float t;
            t = fmaf(xv[q].x, inv, -aa.x) + 1e-6f;  sap = fmaf(t, t, sap);
            t = fmaf(xv[q].y, inv, -aa.y) + 1e-6f;  sap = fmaf(t, t, sap);
            t = fmaf(xv[q].z, inv, -aa.z) + 1e-6f;  sap = fmaf(t, t, sap);
            t = fmaf(xv[q].w, inv, -aa.w) + 1e-6f;  sap = fmaf(t, t, sap);
            t = fmaf(xv[q].x, inv, -nn.x) + 1e-6f;  san = fmaf(t, t, san);
            t = fmaf(xv[q].y, inv, -nn.y) + 1e-6f;  san = fmaf(t, t, san);
            t = fmaf(xv[q].z, inv, -nn.z) + 1e-6f;  san = fmaf(t, t, san);
            t = fmaf(xv[q].w, inv, -nn.w) + 1e-6f;  san = fmaf(t, t, san);
        }
        sap += __shfl_xor(sap, 1);  sap += __shfl_xor(sap, 2);
        san += __shfl_xor(san, 1);  san += __shfl_xor(san, 2);
        if (p4 == 0) {
            float tri = fmaxf(sqrtf(sap) - sqrtf(san) + 0.2f, 0.0f);
            float w   = label[b * C + cg];
            num = tri * w;
            den = w;
        }
    }

    #pragma unroll
    for (int off = 1; off < 64; off <<= 1) {
        num += __shfl_xor(num, off);
        den += __shfl_xor(den, off);
    }
    if (lane == 0) { wred[wid * 2] = num; wred[wid * 2 + 1] = den; }
    __syncthreads();

    if (tid == 0) {
        float sn = 0.f, sd = 0.f;
        #pragma unroll
        for (int wv = 0; wv < 8; wv++) { sn += wred[wv * 2]; sd += wred[wv * 2 + 1]; }
        part[blk * 2 + 0] = sn;
        part[blk * 2 + 1] = sd;
    }
}

__global__ void triplet_finish(const float* __restrict__ part, float* __restrict__ out)
{
    int t = threadIdx.x;  // 64 threads = 1 wave; t = batch index
    float num = 0.f, den = 0.f;
    #pragma unroll
    for (int h = 0; h < 8; h++) {
        num += part[(t * 8 + h) * 2 + 0];
        den += part[(t * 8 + h) * 2 + 1];
    }
    float v = num / den;
    #pragma unroll
    for (int off = 32; off > 0; off >>= 1) v += __shfl_down(v, off);
    if (t == 0) out[0] = v * (1.0f / (float)BS);
}

extern "C" void kernel_launch(void* const* d_in, const int* in_sizes, int n_in,
                              void* d_out, int out_size, void* d_ws, size_t ws_size,
                              hipStream_t stream)
{
    const float* inputs = (const float*)d_in[0];
    const float* label  = (const float*)d_in[1];
    const float* prot   = (const float*)d_in[2];
    float* out = (float*)d_out;

    ushort_t* phg   = (ushort_t*)d_ws;                  // 128 KB
    uint_t*   pkeys = (uint_t*)(phg + (size_t)C * D);   // 512 KB (2 x 64K)
    float*    part  = (float*)(pkeys + 2 * BS * C);     // 4 KB

    prep_prot<<<dim3(C / 128), dim3(128), 0, stream>>>(prot, phg);
    triplet_keys<<<dim3(BS * (C / CT) * 2), dim3(512), 0, stream>>>(inputs, phg, pkeys);
    triplet_loss<<<dim3(BS * (C / CT)), dim3(512), 0, stream>>>(
        inputs, label, prot, pkeys, part);
    triplet_finish<<<1, 64, 0, stream>>>(part, out);
}

// Round 13
// 40.601 us; speedup vs baseline: 1.4132x; 1.4132x over previous
//
#include <hip/hip_runtime.h>
#include <cfloat>

#define BS 64
#define C  1024
#define D  64
#define CT 64

typedef __attribute__((ext_vector_type(8))) short short8;
typedef __attribute__((ext_vector_type(4))) float f32x4;
typedef unsigned short ushort_t;
typedef unsigned int uint_t;

__device__ __forceinline__ ushort_t f2bf(float f) {
    uint_t u = __float_as_uint(f);
    u += 0x7fffu + ((u >> 16) & 1u);          // round-to-nearest-even
    return (ushort_t)(u >> 16);
}

// ---- prep: bf16 prototypes frag-ordered (prot only, 8 blocks) ----
// short8 idx = jt*128 + h*64 + ln;  jt=k>>4, h=K-half, ln=(k&15)+kslot*16
__global__ void prep_prot(const float* __restrict__ prot, ushort_t* __restrict__ ph)
{
    const int k = blockIdx.x * 128 + threadIdx.x;   // 0..1023
    const float4* row = (const float4*)(prot + (size_t)k * D);
    const int jt = k >> 4;
    #pragma unroll
    for (int dg = 0; dg < 8; dg++) {
        float4 a = row[dg * 2];
        float4 b = row[dg * 2 + 1];
        float x[8] = {a.x, a.y, a.z, a.w, b.x, b.y, b.z, b.w};
        short8 hv;
        #pragma unroll
        for (int e = 0; e < 8; e++) hv[e] = (short)f2bf(x[e]);
        const int h  = dg >> 2;
        const int ln = (k & 15) + (dg & 3) * 16;
        ((short8*)ph)[(size_t)jt * 128 + h * 64 + ln] = hv;
    }
}

// ---- main: CT=64, grid 1024, <=64 VGPR/wave for 8 waves/SIMD occupancy ----
__global__ __launch_bounds__(512, 8)
void triplet_mfma(const float* __restrict__ inputs,
                  const float* __restrict__ label,
                  const float* __restrict__ prot,
                  const ushort_t* __restrict__ phg,
                  float* __restrict__ part)
{
    __shared__ short8 bsh[16 * 128];     // 32 KB B chunk; first 8 KB doubles as X stage
    __shared__ uint_t redk[CT][2];
    __shared__ float  wred[16];

    const int tid  = threadIdx.x;
    const int lane = tid & 63;
    const int wid  = tid >> 6;     // 0..7
    const int wr   = wid >> 1;     // 0..3 -> one 16-row tile each
    const int wc   = wid & 1;      // 0..1 -> 8 col-tiles per chunk
    const int b    = blockIdx.x >> 4;
    const int ct   = blockIdx.x & 15;
    const int c0   = ct * CT;

    const short8* BH = (const short8*)phg;

    // ---- prologue: convert this block's X (64 rows) to frag-order in LDS ----
    if (tid < 512) {
        const int rel = tid;                  // 0..511 = 4 ft x 128
        const int ft = rel >> 7, w = rel & 127, h = w >> 6, ln = w & 63;
        const int rr = ft * 16 + (ln & 15), dg = h * 4 + (ln >> 4);
        const float* s = inputs + (size_t)(b * C + c0 + rr) * D + dg * 8;
        float4 a  = *(const float4*)s;
        float4 b2 = *(const float4*)(s + 4);
        short8 hv;
        hv[0] = (short)f2bf(a.x);  hv[1] = (short)f2bf(a.y);
        hv[2] = (short)f2bf(a.z);  hv[3] = (short)f2bf(a.w);
        hv[4] = (short)f2bf(b2.x); hv[5] = (short)f2bf(b2.y);
        hv[6] = (short)f2bf(b2.z); hv[7] = (short)f2bf(b2.w);
        bsh[rel] = hv;
    }
    __syncthreads();

    // A fragments: this wave's single 16-row tile
    short8 ah0 = bsh[wr * 128 + lane];
    short8 ah1 = bsh[wr * 128 + 64 + lane];
    __syncthreads();   // frag reads done before chunk 0 overwrites the stage

    uint_t bestk[4];
    bestk[0] = 0u; bestk[1] = 0u; bestk[2] = 0u; bestk[3] = 0u;

    const uint_t MMASK = 0xFFFFFC00u;
    const int rowtile = ct * 4 + wr;          // global 16-row tile index
    const int rsub = (lane >> 4) * 4;
    const int csub = lane & 15;

    auto process = [&](int jg, short8 b0, short8 b1) {
        const uint_t cidx = (uint_t)(1023 - (jg * 16 + csub));
        f32x4 acc = {16.f, 16.f, 16.f, 16.f};   // S_raw+16 > 0: sortable bits
        acc = __builtin_amdgcn_mfma_f32_16x16x32_bf16(ah0, b0, acc, 0, 0, 0);
        acc = __builtin_amdgcn_mfma_f32_16x16x32_bf16(ah1, b1, acc, 0, 0, 0);
        const bool dtile = (rowtile == jg);      // wave-uniform
        #pragma unroll
        for (int r = 0; r < 4; r++) {
            uint_t key = (__float_as_uint(acc[r]) & MMASK) | cidx;
            if (dtile && (rsub + r) == csub) key = 0u;   // mask diagonal
            bestk[r] = bestk[r] > key ? bestk[r] : key;
        }
    };

    // four chunks of 16 col-tiles; per chunk each wave processes 8 from LDS
    for (int ch = 0; ch < 4; ch++) {
        if (ch) __syncthreads();            // prior readers of bsh done
        const short8* src = BH + (size_t)ch * 2048;
        #pragma unroll
        for (int it = 0; it < 4; it++)
            bsh[it * 512 + tid] = src[it * 512 + tid];
        __syncthreads();

        const int base = wc * 8;            // local tile range for this wave
        short8 cb0 = bsh[(base + 0) * 128 + lane];
        short8 cb1 = bsh[(base + 0) * 128 + 64 + lane];
        #pragma unroll
        for (int lt = 0; lt < 8; lt++) {
            const int nt = (lt + 1 < 8) ? lt + 1 : 7;
            short8 n0 = bsh[(base + nt) * 128 + lane];
            short8 n1 = bsh[(base + nt) * 128 + 64 + lane];
            __builtin_amdgcn_sched_barrier(0);
            process(ch * 16 + base + lt, cb0, cb1);
            cb0 = n0; cb1 = n1;
        }
    }

    // cross-lane max over the 16 col-lanes
    #pragma unroll
    for (int r = 0; r < 4; r++) {
        uint_t v = bestk[r];
        #pragma unroll
        for (int off = 1; off < 16; off <<= 1) {
            uint_t ov = (uint_t)__shfl_xor((int)v, off);
            v = v > ov ? v : ov;
        }
        if (csub == 0) redk[wr * 16 + rsub + r][wc] = v;
    }
    __syncthreads();

    // epilogue: 8 threads per row (512 = 8 x 64), exact fp32 norms + d_ap/d_an
    float num = 0.f, den = 0.f;
    {
        const int row = tid >> 3, p8 = tid & 7;
        uint_t k0 = redk[row][0], k1 = redk[row][1];
        uint_t kk = k0 > k1 ? k0 : k1;
        const int bi = 1023 - (int)(kk & 0x3FFu);
        const int cg = c0 + row;

        const float4* xr = (const float4*)(inputs + (size_t)(b * C + cg) * D) + p8 * 2;
        float4 xv[2];
        float x2 = 0.f;
        #pragma unroll
        for (int q = 0; q < 2; q++) {
            xv[q] = xr[q];
            x2 = fmaf(xv[q].x, xv[q].x, fmaf(xv[q].y, xv[q].y,
                 fmaf(xv[q].z, xv[q].z, fmaf(xv[q].w, xv[q].w, x2))));
        }
        x2 += __shfl_xor(x2, 1);
        x2 += __shfl_xor(x2, 2);
        x2 += __shfl_xor(x2, 4);
        const float inv = 1.0f / fmaxf(sqrtf(x2), 1e-12f);

        const float4* pp = (const float4*)(prot + (size_t)cg * D) + p8 * 2;
        const float4* pn = (const float4*)(prot + (size_t)bi * D) + p8 * 2;
        float sap = 0.f, san = 0.f;
        #pragma unroll
        for (int q = 0; q < 2; q++) {
            float4 aa = pp[q];
            float4 nn = pn[q];
            float t;
            t = fmaf(xv[q].x, inv, -aa.x) + 1e-6f;  sap = fmaf(t, t, sap);
            t = fmaf(xv[q].y, inv, -aa.y) + 1e-6f;  sap = fmaf(t, t, sap);
            t = fmaf(xv[q].z, inv, -aa.z) + 1e-6f;  sap = fmaf(t, t, sap);
            t = fmaf(xv[q].w, inv, -aa.w) + 1e-6f;  sap = fmaf(t, t, sap);
            t = fmaf(xv[q].x, inv, -nn.x) + 1e-6f;  san = fmaf(t, t, san);
            t = fmaf(xv[q].y, inv, -nn.y) + 1e-6f;  san = fmaf(t, t, san);
            t = fmaf(xv[q].z, inv, -nn.z) + 1e-6f;  san = fmaf(t, t, san);
            t = fmaf(xv[q].w, inv, -nn.w) + 1e-6f;  san = fmaf(t, t, san);
        }
        #pragma unroll
        for (int off = 1; off < 8; off <<= 1) {
            sap += __shfl_xor(sap, off);
            san += __shfl_xor(san, off);
        }
        if (p8 == 0) {
            float tri = fmaxf(sqrtf(sap) - sqrtf(san) + 0.2f, 0.0f);
            float w   = label[b * C + cg];
            num = tri * w;
            den = w;
        }
    }

    // block reduce: wave shuffles + one barrier, plain per-block store
    #pragma unroll
    for (int off = 1; off < 64; off <<= 1) {
        num += __shfl_xor(num, off);
        den += __shfl_xor(den, off);
    }
    if (lane == 0) { wred[wid * 2] = num; wred[wid * 2 + 1] = den; }
    __syncthreads();

    if (tid == 0) {
        float sn = 0.f, sd = 0.f;
        #pragma unroll
        for (int wv = 0; wv < 8; wv++) { sn += wred[wv * 2]; sd += wred[wv * 2 + 1]; }
        part[blockIdx.x * 2 + 0] = sn;
        part[blockIdx.x * 2 + 1] = sd;
    }
}

__global__ void triplet_finish(const float* __restrict__ part, float* __restrict__ out)
{
    int t = threadIdx.x;  // 64 threads = 1 wave; t = batch index
    float num = 0.f, den = 0.f;
    #pragma unroll
    for (int h = 0; h < 16; h++) {
        num += part[(t * 16 + h) * 2 + 0];
        den += part[(t * 16 + h) * 2 + 1];
    }
    float v = num / den;
    #pragma unroll
    for (int off = 32; off > 0; off >>= 1) v += __shfl_down(v, off);
    if (t == 0) out[0] = v * (1.0f / (float)BS);
}

extern "C" void kernel_launch(void* const* d_in, const int* in_sizes, int n_in,
                              void* d_out, int out_size, void* d_ws, size_t ws_size,
                              hipStream_t stream)
{
    const float* inputs = (const float*)d_in[0];
    const float* label  = (const float*)d_in[1];
    const float* prot   = (const float*)d_in[2];
    float* out = (float*)d_out;

    ushort_t* phg  = (ushort_t*)d_ws;                 // 128 KB
    float*    part = (float*)(phg + (size_t)C * D);   // 8 KB (1024 x 2)

    prep_prot<<<dim3(C / 128), dim3(128), 0, stream>>>(prot, phg);
    triplet_mfma<<<dim3(BS * (C / CT)), dim3(512), 0, stream>>>(
        inputs, label, prot, phg, part);
    triplet_finish<<<1, 64, 0, stream>>>(part, out);
}

// Round 14
// 26.836 us; speedup vs baseline: 2.1381x; 1.5129x over previous
//
#include <hip/hip_runtime.h>
#include <cfloat>

#define BS 64
#define C  1024
#define D  64
#define CT 128

typedef __attribute__((ext_vector_type(8))) short short8;
typedef __attribute__((ext_vector_type(4))) float f32x4;
typedef unsigned short ushort_t;
typedef unsigned int uint_t;

__device__ __forceinline__ ushort_t f2bf(float f) {
    uint_t u = __float_as_uint(f);
    u += 0x7fffu + ((u >> 16) & 1u);          // round-to-nearest-even
    return (ushort_t)(u >> 16);
}

// ---- prep: bf16 prototypes frag-ordered (prot only, 8 blocks) ----
// short8 idx = jt*128 + h*64 + ln;  jt=k>>4, h=K-half, ln=(k&15)+kslot*16
__global__ void prep_prot(const float* __restrict__ prot, ushort_t* __restrict__ ph)
{
    const int k = blockIdx.x * 128 + threadIdx.x;   // 0..1023
    const float4* row = (const float4*)(prot + (size_t)k * D);
    const int jt = k >> 4;
    #pragma unroll
    for (int dg = 0; dg < 8; dg++) {
        float4 a = row[dg * 2];
        float4 b = row[dg * 2 + 1];
        float x[8] = {a.x, a.y, a.z, a.w, b.x, b.y, b.z, b.w};
        short8 hv;
        #pragma unroll
        for (int e = 0; e < 8; e++) hv[e] = (short)f2bf(x[e]);
        const int h  = dg >> 2;
        const int ln = (k & 15) + (dg & 3) * 16;
        ((short8*)ph)[(size_t)jt * 128 + h * 64 + ln] = hv;
    }
}

// ---- main: async double-buffered B staging (global_load_lds), raw-x argmax ----
__global__ __launch_bounds__(512, 4)
void triplet_mfma(const float* __restrict__ inputs,
                  const float* __restrict__ label,
                  const float* __restrict__ prot,
                  const ushort_t* __restrict__ phg,
                  float* __restrict__ part)
{
    __shared__ short8 bufA[2048];        // 32 KB B chunk buffer (even chunks)
    __shared__ short8 bufB[2048];        // 32 KB B chunk buffer (odd); first 16 KB = X stage
    __shared__ uint_t redk[CT][4];
    __shared__ float  wred[16];

    const int tid  = threadIdx.x;
    const int lane = tid & 63;
    const int wid  = tid >> 6;     // 0..7
    const int wr   = wid >> 2;     // 0..1 -> 64 c-rows
    const int wc   = wid & 3;      // 0..3 -> 4 col-tiles per 16-tile chunk
    const int b    = blockIdx.x >> 3;
    const int c0   = (blockIdx.x & 7) * CT;

    const short8* BH = (const short8*)phg;

    // async stage of one 32 KB chunk: per wave 4 x (64 lanes x 16 B), linear
    auto stage = [&](const short8* src, short8* dst) {
        #pragma unroll
        for (int it = 0; it < 4; it++) {
            __builtin_amdgcn_global_load_lds(
                (const __attribute__((address_space(1))) void*)(src + wid * 256 + it * 64 + lane),
                (__attribute__((address_space(3))) void*)(dst + wid * 256 + it * 64),
                16, 0, 0);
        }
    };

    // issue chunk 0 immediately; its L2 latency hides under the X convert
    stage(BH, bufA);

    // ---- prologue: convert this block's X (128 rows) to frag-order in bufB ----
    #pragma unroll
    for (int it = 0; it < 2; it++) {
        const int rel = tid + it * 512;       // 0..1023
        const int ft = rel >> 7, w = rel & 127, h = w >> 6, ln = w & 63;
        const int rr = ft * 16 + (ln & 15), dg = h * 4 + (ln >> 4);
        const float* s = inputs + (size_t)(b * C + c0 + rr) * D + dg * 8;
        float4 a  = *(const float4*)s;
        float4 b2 = *(const float4*)(s + 4);
        short8 hv;
        hv[0] = (short)f2bf(a.x);  hv[1] = (short)f2bf(a.y);
        hv[2] = (short)f2bf(a.z);  hv[3] = (short)f2bf(a.w);
        hv[4] = (short)f2bf(b2.x); hv[5] = (short)f2bf(b2.y);
        hv[6] = (short)f2bf(b2.z); hv[7] = (short)f2bf(b2.w);
        bufB[rel] = hv;
    }
    __syncthreads();

    // A fragments for this wave's 64 rows (lane-contiguous LDS reads)
    short8 ah[4][2];
    #pragma unroll
    for (int i = 0; i < 4; i++) {
        ah[i][0] = bufB[(wr * 4 + i) * 128 + lane];
        ah[i][1] = bufB[(wr * 4 + i) * 128 + 64 + lane];
    }
    __syncthreads();   // A-frag reads done before chunk 1 overwrites bufB

    uint_t bestk[16];
    #pragma unroll
    for (int q = 0; q < 16; q++) bestk[q] = 0u;

    const uint_t MMASK = 0xFFFFFC00u;
    const int rowtile0 = (c0 >> 4) + wr * 4;
    const int rsub = (lane >> 4) * 4;
    const int csub = lane & 15;

    auto process = [&](int jg, short8 b0, short8 b1) {
        const uint_t cidx = (uint_t)(1023 - (jg * 16 + csub));
        #pragma unroll
        for (int i = 0; i < 4; i++) {
            f32x4 acc = {16.f, 16.f, 16.f, 16.f};   // S_raw+16 > 0: sortable bits
            acc = __builtin_amdgcn_mfma_f32_16x16x32_bf16(ah[i][0], b0, acc, 0, 0, 0);
            acc = __builtin_amdgcn_mfma_f32_16x16x32_bf16(ah[i][1], b1, acc, 0, 0, 0);
            const bool dtile = (rowtile0 + i) == jg;   // wave-uniform
            #pragma unroll
            for (int r = 0; r < 4; r++) {
                uint_t key = (__float_as_uint(acc[r]) & MMASK) | cidx;
                if (dtile && (rsub + r) == csub) key = 0u;   // mask diagonal
                bestk[i * 4 + r] = bestk[i * 4 + r] > key ? bestk[i * 4 + r] : key;
            }
        }
    };

    // 4 chunks x 16 col-tiles, double-buffered: barrier drains the loads
    // issued one compute-phase earlier, next chunk issues right after.
    for (int ch = 0; ch < 4; ch++) {
        __syncthreads();                      // chunk ch resident (vmcnt drained)
        short8* cur = (ch & 1) ? bufB : bufA;
        if (ch < 3) stage(BH + (size_t)(ch + 1) * 2048, (ch & 1) ? bufA : bufB);

        const int base = wc * 4;              // this wave's 4 tiles in the chunk
        short8 cb0 = cur[(base + 0) * 128 + lane];
        short8 cb1 = cur[(base + 0) * 128 + 64 + lane];
        #pragma unroll
        for (int lt = 0; lt < 4; lt++) {
            const int nt = (lt + 1 < 4) ? lt + 1 : 3;
            short8 n0 = cur[(base + nt) * 128 + lane];
            short8 n1 = cur[(base + nt) * 128 + 64 + lane];
            __builtin_amdgcn_sched_barrier(0);
            process(ch * 16 + base + lt, cb0, cb1);
            cb0 = n0; cb1 = n1;
        }
    }

    // cross-lane max over the 16 col-lanes
    #pragma unroll
    for (int i = 0; i < 4; i++)
        #pragma unroll
        for (int r = 0; r < 4; r++) {
            uint_t v = bestk[i * 4 + r];
            #pragma unroll
            for (int off = 1; off < 16; off <<= 1) {
                uint_t ov = (uint_t)__shfl_xor((int)v, off);
                v = v > ov ? v : ov;
            }
            if (csub == 0) redk[wr * 64 + i * 16 + rsub + r][wc] = v;
        }
    __syncthreads();

    // epilogue: 4 threads per row (512 = 4 x 128), exact fp32 norms + d_ap/d_an
    float num = 0.f, den = 0.f;
    {
        const int row = tid >> 2, p4 = tid & 3;
        uint_t kk = redk[row][p4];
        {
            uint_t o1 = (uint_t)__shfl_xor((int)kk, 1); kk = kk > o1 ? kk : o1;
            uint_t o2 = (uint_t)__shfl_xor((int)kk, 2); kk = kk > o2 ? kk : o2;
        }
        const int bi = 1023 - (int)(kk & 0x3FFu);
        const int cg = c0 + row;

        const float4* xr = (const float4*)(inputs + (size_t)(b * C + cg) * D) + p4 * 4;
        float4 xv[4];
        float x2 = 0.f;
        #pragma unroll
        for (int q = 0; q < 4; q++) {
            xv[q] = xr[q];
            x2 = fmaf(xv[q].x, xv[q].x, fmaf(xv[q].y, xv[q].y,
                 fmaf(xv[q].z, xv[q].z, fmaf(xv[q].w, xv[q].w, x2))));
        }
        x2 += __shfl_xor(x2, 1);
        x2 += __shfl_xor(x2, 2);
        const float inv = 1.0f / fmaxf(sqrtf(x2), 1e-12f);

        const float4* pp = (const float4*)(prot + (size_t)cg * D) + p4 * 4;
        const float4* pn = (const float4*)(prot + (size_t)bi * D) + p4 * 4;
        float sap = 0.f, san = 0.f;
        #pragma unroll
        for (int q = 0; q < 4; q++) {
            float4 aa = pp[q];
            float4 nn = pn[q];
            float t;
            t = fmaf(xv[q].x, inv, -aa.x) + 1e-6f;  sap = fmaf(t, t, sap);
            t = fmaf(xv[q].y, inv, -aa.y) + 1e-6f;  sap = fmaf(t, t, sap);
            t = fmaf(xv[q].z, inv, -aa.z) + 1e-6f;  sap = fmaf(t, t, sap);
            t = fmaf(xv[q].w, inv, -aa.w) + 1e-6f;  sap = fmaf(t, t, sap);
            t = fmaf(xv[q].x, inv, -nn.x) + 1e-6f;  san = fmaf(t, t, san);
            t = fmaf(xv[q].y, inv, -nn.y) + 1e-6f;  san = fmaf(t, t, san);
            t = fmaf(xv[q].z, inv, -nn.z) + 1e-6f;  san = fmaf(t, t, san);
            t = fmaf(xv[q].w, inv, -nn.w) + 1e-6f;  san = fmaf(t, t, san);
        }
        sap += __shfl_xor(sap, 1);  sap += __shfl_xor(sap, 2);
        san += __shfl_xor(san, 1);  san += __shfl_xor(san, 2);
        if (p4 == 0) {
            float tri = fmaxf(sqrtf(sap) - sqrtf(san) + 0.2f, 0.0f);
            float w   = label[b * C + cg];
            num = tri * w;
            den = w;
        }
    }

    // block reduce: wave shuffles + one barrier, plain per-block store
    #pragma unroll
    for (int off = 1; off < 64; off <<= 1) {
        num += __shfl_xor(num, off);
        den += __shfl_xor(den, off);
    }
    if (lane == 0) { wred[wid * 2] = num; wred[wid * 2 + 1] = den; }
    __syncthreads();

    if (tid == 0) {
        float sn = 0.f, sd = 0.f;
        #pragma unroll
        for (int wv = 0; wv < 8; wv++) { sn += wred[wv * 2]; sd += wred[wv * 2 + 1]; }
        part[blockIdx.x * 2 + 0] = sn;
        part[blockIdx.x * 2 + 1] = sd;
    }
}

__global__ void triplet_finish(const float* __restrict__ part, float* __restrict__ out)
{
    int t = threadIdx.x;  // 64 threads = 1 wave; t = batch index
    float num = 0.f, den = 0.f;
    #pragma unroll
    for (int h = 0; h < 8; h++) {
        num += part[(t * 8 + h) * 2 + 0];
        den += part[(t * 8 + h) * 2 + 1];
    }
    float v = num / den;
    #pragma unroll
    for (int off = 32; off > 0; off >>= 1) v += __shfl_down(v, off);
    if (t == 0) out[0] = v * (1.0f / (float)BS);
}

extern "C" void kernel_launch(void* const* d_in, const int* in_sizes, int n_in,
                              void* d_out, int out_size, void* d_ws, size_t ws_size,
                              hipStream_t stream)
{
    const float* inputs = (const float*)d_in[0];
    const float* label  = (const float*)d_in[1];
    const float* prot   = (const float*)d_in[2];
    float* out = (float*)d_out;

    ushort_t* phg  = (ushort_t*)d_ws;                 // 128 KB
    float*    part = (float*)(phg + (size_t)C * D);   // 4 KB

    prep_prot<<<dim3(C / 128), dim3(128), 0, stream>>>(prot, phg);
    triplet_mfma<<<dim3(BS * (C / CT)), dim3(512), 0, stream>>>(
        inputs, label, prot, phg, part);
    triplet_finish<<<1, 64, 0, stream>>>(part, out);
}